// Round 7
// baseline (108.287 us; speedup 1.0000x reference)
//
#include <hip/hip_runtime.h>

#define NA 8192
#define IT 128                          // i-atoms per wave-job (2 per lane, packed)
#define JT 32                           // j-atoms per wave-job (half-tile, readlane-fed)
#define NI (NA / IT)                    // 64 i-tile rows
#define NJOB 8320                       // sum_{I=0..63} (256 - 4I) jobs with Jh >= 4I
#define WPB 4                           // waves per block
#define BLOCK (WPB * 64)                // 256 threads
#define NBLK (NJOB / WPB)               // 2080 blocks (divides exactly)
#define S_OF(I) (2 * (I) * (129 - (I))) // jobs before i-tile row I (monotone, I<=64)

typedef float v2f __attribute__((ext_vector_type(2)));

__device__ __forceinline__ float bcast(float v, int k) {
    return __int_as_float(__builtin_amdgcn_readlane(__float_as_int(v), k));
}

// launch_bounds(256,8): 8 waves/EU resident (VGPR<=64) -- TLP hides the ~60cyc
// per-body dependency chain that capped R6 at ~32% VALU-pipe busy.
__global__ __launch_bounds__(BLOCK, 8) void dftd3_pair_energy(
    const float* __restrict__ pos,
    const float* __restrict__ p_a1, const float* __restrict__ p_a2,
    const float* __restrict__ p_s6, const float* __restrict__ p_s8,
    float* __restrict__ partial, int* __restrict__ cnt,
    float* __restrict__ out)
{
    const int tid  = threadIdx.x;
    const int lane = tid & 63;
    const int w = __builtin_amdgcn_readfirstlane(blockIdx.x * WPB + (tid >> 6));

    // ---- decode w -> (I, Jh) with Jh in [4I, 256)
    int I = (int)((258.0f - sqrtf(66564.0f - 8.0f * (float)w)) * 0.25f);
    if (I < 0) I = 0;
    if (I > NI - 1) I = NI - 1;
    while (S_OF(I + 1) <= w) ++I;       // integer fixup for sqrt rounding
    while (S_OF(I) > w) --I;
    const int Jh = 4 * I + (w - S_OF(I));
    const bool edge = (w - S_OF(I)) < 4;   // half-tiles overlapping j<=i cells

    // ---- positions pre-scaled by 2^-6 (exact): d6' = 2^-36 d6, d8' = 2^-48 d8
    const float PS = 0.015625f;            // 2^-6
    const int j = Jh * JT + (lane & 31);   // 32 j-atoms, duplicated across half-waves
    const float vxj = pos[3 * j + 0] * PS;
    const float vyj = pos[3 * j + 1] * PS;
    const float vzj = pos[3 * j + 2] * PS;

    const int i0 = I * IT + 2 * lane;      // lane owns atoms i0, i0+1
    const v2f xi = { pos[3 * i0 + 0] * PS, pos[3 * i0 + 3] * PS };
    const v2f yi = { pos[3 * i0 + 1] * PS, pos[3 * i0 + 4] * PS };
    const v2f zi = { pos[3 * i0 + 2] * PS, pos[3 * i0 + 5] * PS };

    const float a1 = p_a1[0], a2 = p_a2[0];
    const float s6 = p_s6[0], s8 = p_s8[0];
    const float tmp  = a1 + a2;
    const float tmp2 = tmp * tmp;
    const float tmp6 = tmp2 * tmp2 * tmp2;
    const float tmp8 = tmp6 * tmp2;
    const float T6s = (tmp6 + 1e-12f) * 1.4551915e-11f;   // *2^-36
    const float T8s = (tmp8 + 1e-12f) * 3.5527137e-15f;   // *2^-48
    // fold pair-doubling (x2) and the scale into numerator constants
    const float c6 = -2.0f * s6 * 1.4551915e-11f;
    const float c8 = -2.0f * s8 * 3.5527137e-15f;

    // two accumulator pairs (k-parity) to halve the acc dependency chain
    v2f accA = {0.0f, 0.0f}, accB = {0.0f, 0.0f};

    auto body = [&](int k, bool masked) {
        float sx = bcast(vxj, k);          // j-atom k broadcast (SGPR splat)
        float sy = bcast(vyj, k);
        float sz = bcast(vzj, k);
        v2f dx = xi - sx;
        v2f dy = yi - sy;
        v2f dz = zi - sz;
        v2f d2 = __builtin_elementwise_fma(dx, dx,
                 __builtin_elementwise_fma(dy, dy, dz * dz));
        v2f d4 = d2 * d2;
        v2f A  = __builtin_elementwise_fma(d4, d2, (v2f)T6s);  // 2^-36 (d6+T6)
        v2f B  = __builtin_elementwise_fma(d4, d4, (v2f)T8s);  // 2^-48 (d8+T8)
        v2f num = __builtin_elementwise_fma((v2f)c6, B, (v2f)c8 * A);
        v2f den = A * B;                   // in [2e-16, 8.8e2]: safe
        float t = den.x * den.y;           // in [4e-32, 7.7e5]: safe
        float r = __builtin_amdgcn_rcpf(t);    // ONE rcp for both pairs
        if (masked) {                      // edge jobs: count only j>i (excludes self)
            const int jk = Jh * JT + k;
            num.x = (jk > i0)     ? num.x : 0.0f;
            num.y = (jk > i0 + 1) ? num.y : 0.0f;
        }
        v2f inv = { den.y * r, den.x * r };    // {1/den.x, 1/den.y}
        if (k & 1) accB = __builtin_elementwise_fma(num, inv, accB);
        else       accA = __builtin_elementwise_fma(num, inv, accA);
    };

    if (edge) {
        #pragma unroll 4
        for (int k = 0; k < JT; ++k) body(k, true);
    } else {
        #pragma unroll 4
        for (int k = 0; k < JT; ++k) body(k, false);
    }

    float acc = (accA.x + accA.y) + (accB.x + accB.y);  // x2 folded into c6/c8

    // ---- wave butterfly, block partial, counter-gated final reduce
    #pragma unroll
    for (int off = 32; off > 0; off >>= 1)
        acc += __shfl_xor(acc, off, 64);

    __shared__ float wsum[WPB];
    __shared__ int lastflag;
    if (lane == 0) wsum[tid >> 6] = acc;
    __syncthreads();
    if (tid == 0) {
        float s = 0.0f;
        #pragma unroll
        for (int q = 0; q < WPB; ++q) s += wsum[q];
        atomicExch(&partial[blockIdx.x], s);   // device-coherent block sum
        __threadfence();                       // release: partial before counter
        int old = atomicAdd(cnt, 1);
        lastflag = (old == NBLK - 1);
    }
    __syncthreads();
    if (lastflag) {
        __threadfence();                       // acquire
        float s = 0.0f;
        for (int t = tid; t < NBLK; t += BLOCK)
            s += atomicAdd(&partial[t], 0.0f); // coherent read
        #pragma unroll
        for (int off = 32; off > 0; off >>= 1)
            s += __shfl_xor(s, off, 64);
        if (lane == 0) wsum[tid >> 6] = s;
        __syncthreads();
        if (tid == 0) {
            float tot = 0.0f;
            #pragma unroll
            for (int q = 0; q < WPB; ++q) tot += wsum[q];
            out[0] = tot;
        }
    }
}

extern "C" void kernel_launch(void* const* d_in, const int* in_sizes, int n_in,
                              void* d_out, int out_size, void* d_ws, size_t ws_size,
                              hipStream_t stream) {
    // setup_inputs order: atomic_numbers(0), positions(1), r2r4(2), a1(3), a2(4), s6(5), s8(6)
    const float* pos = (const float*)d_in[1];
    const float* a1  = (const float*)d_in[3];
    const float* a2  = (const float*)d_in[4];
    const float* s6  = (const float*)d_in[5];
    const float* s8  = (const float*)d_in[6];
    float* partial = (float*)d_ws;                    // NBLK block sums
    int*   cnt     = (int*)((char*)d_ws + 65536);     // arrival counter
    float* out     = (float*)d_out;

    hipMemsetAsync(cnt, 0, sizeof(int), stream);      // 4 bytes only

    dftd3_pair_energy<<<dim3(NBLK), BLOCK, 0, stream>>>(pos, a1, a2, s6, s8,
                                                        partial, cnt, out);
}

// Round 8
// 96.294 us; speedup vs baseline: 1.1245x; 1.1245x over previous
//
#include <hip/hip_runtime.h>

#define NA 8192
#define TI 128                          // i-atoms per wave-job (2 per lane, packed)
#define TJ 128                          // j-atoms per wave-job (two 64-wide readlane sets)
#define NT (NA / TI)                    // 64 tiles per dimension (TI == TJ)
#define NJOB (NT * (NT + 1) / 2)        // 2080 upper-triangular tile jobs, one per WAVE
#define WPB 2                           // waves per block
#define BLOCK (WPB * 64)                // 128 threads
#define NBLK (NJOB / WPB)               // 1040 blocks
#define NSLOT 64                        // salted partial slots (L2-line spaced)
#define SLOT_STRIDE 16                  // floats: 64 B per slot
#define S_OF(r) ((r) * NT - (r) * ((r) - 1) / 2)

typedef float v2f __attribute__((ext_vector_type(2)));

__device__ __forceinline__ float bcast(float v, int k) {
    return __int_as_float(__builtin_amdgcn_readlane(__float_as_int(v), k));
}

__global__ __launch_bounds__(BLOCK, 4) void dftd3_pair_energy(
    const float* __restrict__ pos,
    const float* __restrict__ p_a1, const float* __restrict__ p_a2,
    const float* __restrict__ p_s6, const float* __restrict__ p_s8,
    float* __restrict__ slots, int* __restrict__ cnt,
    float* __restrict__ out)
{
    const int tid  = threadIdx.x;
    const int lane = tid & 63;
    const int w = __builtin_amdgcn_readfirstlane(blockIdx.x * WPB + (tid >> 6));

    // ---- decode wave-job -> upper-triangular (I, J), 64x64 tiles
    int I = (int)((129.0f - sqrtf(16641.0f - 8.0f * (float)w)) * 0.5f);
    if (I < 0) I = 0;
    if (I > NT - 1) I = NT - 1;
    while (S_OF(I + 1) <= w) ++I;
    while (S_OF(I) > w) --I;
    const int J = I + (w - S_OF(I));

    // ---- positions pre-scaled by 2^-6 (exact): d6' = 2^-36 d6, d8' = 2^-48 d8
    const float PS = 0.015625f;
    const int i0 = I * TI + 2 * lane;      // lane owns i-atoms i0, i0+1
    const v2f xi = { pos[3 * i0 + 0] * PS, pos[3 * i0 + 3] * PS };
    const v2f yi = { pos[3 * i0 + 1] * PS, pos[3 * i0 + 4] * PS };
    const v2f zi = { pos[3 * i0 + 2] * PS, pos[3 * i0 + 5] * PS };

    const int jb = J * TJ + lane;          // two 64-atom j-sets held in VGPRs
    const float vxj0 = pos[3 * jb + 0] * PS;
    const float vyj0 = pos[3 * jb + 1] * PS;
    const float vzj0 = pos[3 * jb + 2] * PS;
    const float vxj1 = pos[3 * (jb + 64) + 0] * PS;
    const float vyj1 = pos[3 * (jb + 64) + 1] * PS;
    const float vzj1 = pos[3 * (jb + 64) + 2] * PS;

    const float a1 = p_a1[0], a2 = p_a2[0];
    const float s6 = p_s6[0], s8 = p_s8[0];
    const float tmp  = a1 + a2;
    const float tmp2 = tmp * tmp;
    const float tmp6 = tmp2 * tmp2 * tmp2;
    const float tmp8 = tmp6 * tmp2;
    const float T6s = (tmp6 + 1e-12f) * 1.4551915e-11f;   // *2^-36
    const float T8s = (tmp8 + 1e-12f) * 3.5527137e-15f;   // *2^-48
    const float c6 = -2.0f * s6 * 1.4551915e-11f;         // fold (i,j)+(j,i) doubling
    const float c8 = -2.0f * s8 * 3.5527137e-15f;

    v2f accA = {0.0f, 0.0f}, accB = {0.0f, 0.0f};         // k-parity split

    auto body = [&](float jx, float jy, float jz, int jk, bool masked, bool par) {
        v2f dx = xi - jx;                  // jx/jy/jz are SGPR splats (readlane)
        v2f dy = yi - jy;
        v2f dz = zi - jz;
        v2f d2 = __builtin_elementwise_fma(dx, dx,
                 __builtin_elementwise_fma(dy, dy, dz * dz));
        v2f d4 = d2 * d2;
        v2f A  = __builtin_elementwise_fma(d4, d2, (v2f)T6s);  // 2^-36 (d6+T6)
        v2f B  = __builtin_elementwise_fma(d4, d4, (v2f)T8s);  // 2^-48 (d8+T8)
        v2f num = __builtin_elementwise_fma((v2f)c6, B, (v2f)c8 * A);
        v2f den = A * B;                   // [2e-16, 8.8e2]: safe
        float t = den.x * den.y;           // [4e-32, 7.7e5]: safe
        float r = __builtin_amdgcn_rcpf(t);    // ONE rcp per 2 pairs
        if (masked) {                      // diagonal tile: count j>i only
            num.x = (jk > i0)     ? num.x : 0.0f;
            num.y = (jk > i0 + 1) ? num.y : 0.0f;
        }
        v2f inv = { den.y * r, den.x * r };
        if (par) accB = __builtin_elementwise_fma(num, inv, accB);
        else     accA = __builtin_elementwise_fma(num, inv, accA);
    };

    if (I == J) {                          // 64 diagonal jobs
        #pragma unroll 8
        for (int k = 0; k < 64; ++k)
            body(bcast(vxj0, k), bcast(vyj0, k), bcast(vzj0, k),
                 J * TJ + k, true, k & 1);
        #pragma unroll 8
        for (int k = 0; k < 64; ++k)
            body(bcast(vxj1, k), bcast(vyj1, k), bcast(vzj1, k),
                 J * TJ + 64 + k, true, k & 1);
    } else {                               // 2016 full tiles
        #pragma unroll 8
        for (int k = 0; k < 64; ++k)
            body(bcast(vxj0, k), bcast(vyj0, k), bcast(vzj0, k), 0, false, k & 1);
        #pragma unroll 8
        for (int k = 0; k < 64; ++k)
            body(bcast(vxj1, k), bcast(vyj1, k), bcast(vzj1, k), 0, false, k & 1);
    }

    float acc = (accA.x + accA.y) + (accB.x + accB.y);

    // ---- wave butterfly, block combine, salted atomic
    #pragma unroll
    for (int off = 32; off > 0; off >>= 1)
        acc += __shfl_xor(acc, off, 64);

    __shared__ float wsum[WPB];
    __shared__ int lastflag;
    if (lane == 0) wsum[tid >> 6] = acc;
    __syncthreads();
    if (tid == 0) {
        float s = wsum[0] + wsum[1];
        atomicAdd(&slots[(blockIdx.x & (NSLOT - 1)) * SLOT_STRIDE], s);
        __threadfence();                   // release: slot update before counter
        int old = atomicAdd(cnt, 1);
        lastflag = (old == NBLK - 1);
    }
    __syncthreads();
    if (lastflag) {                        // last block: 64 pipelined coherent loads
        __threadfence();                   // acquire
        float s = 0.0f;
        if (tid < NSLOT)
            s = __hip_atomic_load(&slots[tid * SLOT_STRIDE],
                                  __ATOMIC_ACQUIRE, __HIP_MEMORY_SCOPE_AGENT);
        #pragma unroll
        for (int off = 32; off > 0; off >>= 1)
            s += __shfl_xor(s, off, 64);
        if (lane == 0) wsum[tid >> 6] = s;
        __syncthreads();
        if (tid == 0) out[0] = wsum[0] + wsum[1];   // slots live only in wave 0
    }
}

extern "C" void kernel_launch(void* const* d_in, const int* in_sizes, int n_in,
                              void* d_out, int out_size, void* d_ws, size_t ws_size,
                              hipStream_t stream) {
    // setup_inputs order: atomic_numbers(0), positions(1), r2r4(2), a1(3), a2(4), s6(5), s8(6)
    const float* pos = (const float*)d_in[1];
    const float* a1  = (const float*)d_in[3];
    const float* a2  = (const float*)d_in[4];
    const float* s6  = (const float*)d_in[5];
    const float* s8  = (const float*)d_in[6];
    float* slots = (float*)d_ws;                      // 64 line-spaced accumulators
    int*   cnt   = (int*)((char*)d_ws + NSLOT * SLOT_STRIDE * sizeof(float));
    float* out   = (float*)d_out;

    // zero slots (4 KB) + counter (4 B) in one async memset
    hipMemsetAsync(d_ws, 0, NSLOT * SLOT_STRIDE * sizeof(float) + sizeof(int), stream);

    dftd3_pair_energy<<<dim3(NBLK), BLOCK, 0, stream>>>(pos, a1, a2, s6, s8,
                                                        slots, cnt, out);
}

// Round 9
// 91.050 us; speedup vs baseline: 1.1893x; 1.0576x over previous
//
#include <hip/hip_runtime.h>

#define NA 8192
#define IT 128                          // i-atoms per wave-job (2 per lane, packed)
#define JT 64                           // j-atoms per wave-job (readlane-fed)
#define NI (NA / IT)                    // 64 i-tile rows
#define NJOB 4160                       // jobs with J >= 2I over 64x128 tiles
#define WPB 8                           // waves per block
#define BLOCK (WPB * 64)                // 512 threads
#define NBLK (NJOB / WPB)               // 520 blocks
#define NSLOT 64                        // salted partial slots (L2-line spaced)
#define SLOT_STRIDE 16                  // floats: 64 B per slot
#define NCH 4                           // manually interleaved chains (ILP)
#define S_OF(I) ((I) * (129 - (I)))     // jobs before i-tile row I

typedef float v2f __attribute__((ext_vector_type(2)));

__device__ __forceinline__ float bcast(float v, int k) {
    return __int_as_float(__builtin_amdgcn_readlane(__float_as_int(v), k));
}

// (512,4): 4 waves/EU -> VGPR cap 128. We WANT ~100 VGPRs: 4 independent
// body-chains in flight per wave (R1..R8 ran at VGPR 28-36 = zero ILP,
// VALUBusy pinned at 22% with waves stalled on the ~100cyc dependency chain).
__global__ __launch_bounds__(BLOCK, 4) void dftd3_pair_energy(
    const float* __restrict__ pos,
    const float* __restrict__ p_a1, const float* __restrict__ p_a2,
    const float* __restrict__ p_s6, const float* __restrict__ p_s8,
    float* __restrict__ slots, int* __restrict__ cnt,
    float* __restrict__ out)
{
    const int tid  = threadIdx.x;
    const int lane = tid & 63;
    const int w = __builtin_amdgcn_readfirstlane(blockIdx.x * WPB + (tid >> 6));

    // ---- decode w -> (I, J) with J in [2I, 128)
    int I = (int)((129.0f - sqrtf(16641.0f - 4.0f * (float)w)) * 0.5f);
    if (I < 0) I = 0;
    if (I > NI - 1) I = NI - 1;
    while (S_OF(I + 1) <= w) ++I;
    while (S_OF(I) > w) --I;
    const int J = 2 * I + (w - S_OF(I));
    const bool edge = (w - S_OF(I)) < 2;   // J in {2I, 2I+1}: contains j<=i cells

    // ---- positions pre-scaled by 2^-6 (exact): d6' = 2^-36 d6, d8' = 2^-48 d8
    const float PS = 0.015625f;
    const int j = J * JT + lane;
    const float vxj = pos[3 * j + 0] * PS;   // broadcast source, held in VGPRs
    const float vyj = pos[3 * j + 1] * PS;
    const float vzj = pos[3 * j + 2] * PS;

    const int i0 = I * IT + 2 * lane;        // lane owns atoms i0, i0+1
    const v2f xi = { pos[3 * i0 + 0] * PS, pos[3 * i0 + 3] * PS };
    const v2f yi = { pos[3 * i0 + 1] * PS, pos[3 * i0 + 4] * PS };
    const v2f zi = { pos[3 * i0 + 2] * PS, pos[3 * i0 + 5] * PS };

    const float a1 = p_a1[0], a2 = p_a2[0];
    const float s6 = p_s6[0], s8 = p_s8[0];
    const float tmp  = a1 + a2;
    const float tmp2 = tmp * tmp;
    const float tmp6 = tmp2 * tmp2 * tmp2;
    const float tmp8 = tmp6 * tmp2;
    const float T6s = (tmp6 + 1e-12f) * 1.4551915e-11f;   // *2^-36
    const float T8s = (tmp8 + 1e-12f) * 3.5527137e-15f;   // *2^-48
    const float c6 = -2.0f * s6 * 1.4551915e-11f;         // fold (i,j)+(j,i) doubling
    const float c8 = -2.0f * s8 * 3.5527137e-15f;

    v2f acc[NCH];
    #pragma unroll
    for (int c = 0; c < NCH; ++c) acc[c] = (v2f){0.0f, 0.0f};

    // One "quad": 4 independent chains at lanes k, k+16, k+32, k+48, written
    // stage-by-stage so every stall point has 3 other chains' work adjacent.
    auto quad = [&](int k, bool masked) {
        v2f dx[NCH], dy[NCH], dz[NCH], d2[NCH], d4[NCH];
        v2f A[NCH], B[NCH], num[NCH], den[NCH];
        float r[NCH];
        #pragma unroll
        for (int c = 0; c < NCH; ++c) {
            const int kc = k + 16 * c;
            float sx = bcast(vxj, kc);
            float sy = bcast(vyj, kc);
            float sz = bcast(vzj, kc);
            dx[c] = xi - sx;
            dy[c] = yi - sy;
            dz[c] = zi - sz;
        }
        #pragma unroll
        for (int c = 0; c < NCH; ++c) {
            d2[c] = __builtin_elementwise_fma(dx[c], dx[c],
                    __builtin_elementwise_fma(dy[c], dy[c], dz[c] * dz[c]));
            d4[c] = d2[c] * d2[c];
        }
        #pragma unroll
        for (int c = 0; c < NCH; ++c) {
            A[c] = __builtin_elementwise_fma(d4[c], d2[c], (v2f)T6s);  // 2^-36(d6+T6)
            B[c] = __builtin_elementwise_fma(d4[c], d4[c], (v2f)T8s);  // 2^-48(d8+T8)
        }
        #pragma unroll
        for (int c = 0; c < NCH; ++c) {
            num[c] = __builtin_elementwise_fma((v2f)c6, B[c], (v2f)c8 * A[c]);
            den[c] = A[c] * B[c];          // [2e-16, 8.8e2]: safe
        }
        #pragma unroll
        for (int c = 0; c < NCH; ++c)
            r[c] = __builtin_amdgcn_rcpf(den[c].x * den[c].y);  // t in [4e-32,7.7e5]
        if (masked) {
            #pragma unroll
            for (int c = 0; c < NCH; ++c) {
                const int jk = J * JT + k + 16 * c;
                num[c].x = (jk > i0)     ? num[c].x : 0.0f;
                num[c].y = (jk > i0 + 1) ? num[c].y : 0.0f;
            }
        }
        #pragma unroll
        for (int c = 0; c < NCH; ++c) {
            v2f inv = { den[c].y * r[c], den[c].x * r[c] };
            acc[c] = __builtin_elementwise_fma(num[c], inv, acc[c]);
        }
    };

    if (edge) {
        #pragma unroll 2
        for (int k = 0; k < JT / NCH; ++k) quad(k, true);
    } else {
        #pragma unroll 2
        for (int k = 0; k < JT / NCH; ++k) quad(k, false);
    }

    v2f accv = (acc[0] + acc[1]) + (acc[2] + acc[3]);
    float acc_s = accv.x + accv.y;         // x2 folded into c6/c8

    // ---- wave butterfly, block combine, salted atomic, gated final reduce
    #pragma unroll
    for (int off = 32; off > 0; off >>= 1)
        acc_s += __shfl_xor(acc_s, off, 64);

    __shared__ float wsum[WPB];
    __shared__ int lastflag;
    if (lane == 0) wsum[tid >> 6] = acc_s;
    __syncthreads();
    if (tid == 0) {
        float s = 0.0f;
        #pragma unroll
        for (int q = 0; q < WPB; ++q) s += wsum[q];
        atomicAdd(&slots[(blockIdx.x & (NSLOT - 1)) * SLOT_STRIDE], s);
        __threadfence();                   // release: slot update before counter
        int old = atomicAdd(cnt, 1);
        lastflag = (old == NBLK - 1);
    }
    __syncthreads();
    if (lastflag) {                        // last block: 64 coherent slot loads
        __threadfence();                   // acquire
        float s = 0.0f;
        if (tid < NSLOT)
            s = __hip_atomic_load(&slots[tid * SLOT_STRIDE],
                                  __ATOMIC_ACQUIRE, __HIP_MEMORY_SCOPE_AGENT);
        #pragma unroll
        for (int off = 32; off > 0; off >>= 1)
            s += __shfl_xor(s, off, 64);
        if (lane == 0) wsum[tid >> 6] = s;
        __syncthreads();
        if (tid == 0) out[0] = wsum[0];    // slots live only in wave 0
    }
}

extern "C" void kernel_launch(void* const* d_in, const int* in_sizes, int n_in,
                              void* d_out, int out_size, void* d_ws, size_t ws_size,
                              hipStream_t stream) {
    // setup_inputs order: atomic_numbers(0), positions(1), r2r4(2), a1(3), a2(4), s6(5), s8(6)
    const float* pos = (const float*)d_in[1];
    const float* a1  = (const float*)d_in[3];
    const float* a2  = (const float*)d_in[4];
    const float* s6  = (const float*)d_in[5];
    const float* s8  = (const float*)d_in[6];
    float* slots = (float*)d_ws;                      // 64 line-spaced accumulators
    int*   cnt   = (int*)((char*)d_ws + NSLOT * SLOT_STRIDE * sizeof(float));
    float* out   = (float*)d_out;

    // zero slots (4 KB) + counter (4 B) in one async memset
    hipMemsetAsync(d_ws, 0, NSLOT * SLOT_STRIDE * sizeof(float) + sizeof(int), stream);

    dftd3_pair_energy<<<dim3(NBLK), BLOCK, 0, stream>>>(pos, a1, a2, s6, s8,
                                                        slots, cnt, out);
}

// Round 10
// 89.984 us; speedup vs baseline: 1.2034x; 1.0118x over previous
//
#include <hip/hip_runtime.h>

#define NA 8192
#define WPB 8
#define BLOCK 512
#define NJOB 4224                       // sum over 256 tile-rows of (32 - row/8) chunks
#define NBLK (NJOB / WPB)               // 528 blocks
#define NSLOT 64
#define SLOT_STRIDE 16                  // floats -> 64 B per slot
// ws layout (bytes)
#define AB_OFF   0                      // 8192 atoms x 32 B (A-layout bf16 K-vectors)
#define BB_OFF   262144                 // 8192 x 32 B (B-layout)
#define SI_OFF   524288                 // 8192 x 4 B (|s_eff|^2)
#define SLOT_OFF 557056                 // 64 x 64 B slots
#define CNT_OFF  561152                 // arrival counter

typedef float v2f __attribute__((ext_vector_type(2)));
typedef short short8 __attribute__((ext_vector_type(8)));
typedef float f32x16 __attribute__((ext_vector_type(16)));

__device__ __forceinline__ unsigned bf16rne(float f) {
    unsigned u = __float_as_uint(f);
    return (u + 0x7FFFu + ((u >> 16) & 1u)) >> 16;
}

// Pre-pass: per atom, scaled position split hi/lo into bf16 MFMA K-vectors.
// A-vec k0..11 = [xh,xh,xl,xl, yh,yh,yl,yl, zh,zh,zl,zl]; B-vec = [xh,xl,xh,xl, ...]
// so <A_i,B_j> = sum_coords (h+l)_i (h+l)_j  (all four cross products present).
__global__ __launch_bounds__(256) void prep(const float* __restrict__ pos,
                                            uint4* __restrict__ Ab,
                                            uint4* __restrict__ Bb,
                                            float* __restrict__ Si)
{
    int a = blockIdx.x * 256 + threadIdx.x;
    if (a >= NA) return;
    const float PS = 0.015625f;          // 2^-6 exact pre-scale
    float x = pos[3*a+0] * PS, y = pos[3*a+1] * PS, z = pos[3*a+2] * PS;
    unsigned xh = bf16rne(x); float fxh = __uint_as_float(xh << 16);
    unsigned xl = bf16rne(x - fxh); float fxl = __uint_as_float(xl << 16);
    unsigned yh = bf16rne(y); float fyh = __uint_as_float(yh << 16);
    unsigned yl = bf16rne(y - fyh); float fyl = __uint_as_float(yl << 16);
    unsigned zh = bf16rne(z); float fzh = __uint_as_float(zh << 16);
    unsigned zl = bf16rne(z - fzh); float fzl = __uint_as_float(zl << 16);
    float xe = fxh + fxl, ye = fyh + fyl, ze = fzh + fzl;   // effective coords
    Si[a] = fmaf(xe, xe, fmaf(ye, ye, ze * ze));
    Ab[2*a+0] = make_uint4(xh | (xh<<16), xl | (xl<<16), yh | (yh<<16), yl | (yl<<16));
    Ab[2*a+1] = make_uint4(zh | (zh<<16), zl | (zl<<16), 0u, 0u);
    Bb[2*a+0] = make_uint4(xh | (xl<<16), xh | (xl<<16), yh | (yl<<16), yh | (yl<<16));
    Bb[2*a+1] = make_uint4(zh | (zl<<16), zh | (zl<<16), 0u, 0u);
}

__global__ __launch_bounds__(BLOCK, 4) void dftd3_mfma(
    const uint4* __restrict__ Ab, const uint4* __restrict__ Bb,
    const float* __restrict__ Si,
    const float* __restrict__ p_a1, const float* __restrict__ p_a2,
    const float* __restrict__ p_s6, const float* __restrict__ p_s8,
    float* __restrict__ slots, int* __restrict__ cnt,
    float* __restrict__ out)
{
    const int tid  = threadIdx.x;
    const int lane = tid & 63;
    const int w = __builtin_amdgcn_readfirstlane(blockIdx.x * WPB + (tid >> 6));

    // ---- decode w -> (I tile-row 0..255, Jc 8-tile chunk, Jc >= I>>3)
    // jobs before band q (rows 8q..8q+7): B(q) = 260q - 4q^2
    int q = (int)((260.0f - sqrtf(67600.0f - 16.0f * (float)w)) * 0.125f);
    if (q < 0) q = 0;
    if (q > 31) q = 31;
    while (260*(q+1) - 4*(q+1)*(q+1) <= w) ++q;
    while (260*q - 4*q*q > w) --q;
    int r = w - (260*q - 4*q*q);
    const int u = 32 - q;                 // chunks per row in this band
    int rowoff = 0;
    while (r >= u) { r -= u; ++rowoff; }  // <=7 iterations, scalar
    const int I  = 8*q + rowoff;          // i-tile (32 atoms at 32*I)
    const int Jc = q + r;                 // j-chunk (tiles 8*Jc .. 8*Jc+7)

    const int H = lane >> 5;              // K-half: lanes 0-31 = k0..7, 32-63 = k8..15
    const int c = lane & 31;              // row (A) / col (B,C)

    // A fragment: this lane's i-atom K-half (held for the whole job)
    const short8 af = __builtin_bit_cast(short8, Ab[(32*I + c)*2 + H]);

    // Si quads for this lane's 16 C-rows: rows = {0..3,8..11,16..19,24..27} + 4H
    float4 siq[4];
    const float4* Si4 = (const float4*)Si;
    #pragma unroll
    for (int g = 0; g < 4; ++g) siq[g] = Si4[8*I + 2*g + H];

    const float a1 = p_a1[0], a2 = p_a2[0];
    const float s6 = p_s6[0], s8 = p_s8[0];
    const float tmp  = a1 + a2;
    const float tmp2 = tmp * tmp;
    const float tmp6 = tmp2 * tmp2 * tmp2;
    const float tmp8 = tmp6 * tmp2;
    const float T6s = (tmp6 + 1e-12f) * 1.4551915e-11f;   // (T6+eps) * 2^-36
    const float T8s = (tmp8 + 1e-12f) * 3.5527137e-15f;   // (T8+eps) * 2^-48
    const float c6v = -s6 * 1.4551915e-11f;               // term = c6/A' + c8/B'
    const float c8v = -s8 * 3.5527137e-15f;

    v2f aO = {0.0f, 0.0f};               // off-diagonal tiles (weight 2 at the end)
    v2f aD = {0.0f, 0.0f};               // diagonal tile (weight 1, self masked)

    for (int t = 0; t < 8; ++t) {
        const int J = 8*Jc + t;
        if (J < I) continue;             // wave-uniform skip inside edge chunks
        const short8 bf_ = __builtin_bit_cast(short8, Bb[(32*J + c)*2 + H]);
        const float Sj = Si[32*J + c];
        f32x16 z = {};
        f32x16 C = __builtin_amdgcn_mfma_f32_32x32x16_bf16(af, bf_, z, 0, 0, 0);

        if (J > I) {
            #pragma unroll
            for (int g = 0; g < 4; ++g) {
                float4 s4 = siq[g];
                v2f Sp01 = { s4.x + Sj, s4.y + Sj };
                v2f Sp23 = { s4.z + Sj, s4.w + Sj };
                v2f C01 = { C[4*g+0], C[4*g+1] };
                v2f C23 = { C[4*g+2], C[4*g+3] };
                v2f d2a = __builtin_elementwise_fma(C01, (v2f)(-2.0f), Sp01);
                v2f d2b = __builtin_elementwise_fma(C23, (v2f)(-2.0f), Sp23);
                v2f d4a = d2a * d2a,                  d4b = d2b * d2b;
                v2f Aa = __builtin_elementwise_fma(d4a, d2a, (v2f)T6s);
                v2f Ba = __builtin_elementwise_fma(d4a, d4a, (v2f)T8s);
                v2f Ab_ = __builtin_elementwise_fma(d4b, d2b, (v2f)T6s);
                v2f Bb_ = __builtin_elementwise_fma(d4b, d4b, (v2f)T8s);
                v2f na = __builtin_elementwise_fma((v2f)c6v, Ba, (v2f)c8v * Aa);
                v2f nb = __builtin_elementwise_fma((v2f)c6v, Bb_, (v2f)c8v * Ab_);
                v2f da = Aa * Ba,                     db = Ab_ * Bb_;
                float ra = __builtin_amdgcn_rcpf(da.x * da.y);
                float rb = __builtin_amdgcn_rcpf(db.x * db.y);
                v2f ia = { da.y * ra, da.x * ra };
                v2f ib = { db.y * rb, db.x * rb };
                aO = __builtin_elementwise_fma(na, ia, aO);
                aO = __builtin_elementwise_fma(nb, ib, aO);
            }
        } else {                          // J == I: mask self pairs (row == col)
            #pragma unroll
            for (int g = 0; g < 4; ++g) {
                const int base = 8*g + 4*H;
                float4 s4 = siq[g];
                v2f Sp01 = { s4.x + Sj, s4.y + Sj };
                v2f Sp23 = { s4.z + Sj, s4.w + Sj };
                v2f C01 = { C[4*g+0], C[4*g+1] };
                v2f C23 = { C[4*g+2], C[4*g+3] };
                v2f d2a = __builtin_elementwise_fma(C01, (v2f)(-2.0f), Sp01);
                v2f d2b = __builtin_elementwise_fma(C23, (v2f)(-2.0f), Sp23);
                v2f d4a = d2a * d2a,                  d4b = d2b * d2b;
                v2f Aa = __builtin_elementwise_fma(d4a, d2a, (v2f)T6s);
                v2f Ba = __builtin_elementwise_fma(d4a, d4a, (v2f)T8s);
                v2f Ab_ = __builtin_elementwise_fma(d4b, d2b, (v2f)T6s);
                v2f Bb_ = __builtin_elementwise_fma(d4b, d4b, (v2f)T8s);
                v2f na = __builtin_elementwise_fma((v2f)c6v, Ba, (v2f)c8v * Aa);
                v2f nb = __builtin_elementwise_fma((v2f)c6v, Bb_, (v2f)c8v * Ab_);
                na.x = (c == base + 0) ? 0.0f : na.x;
                na.y = (c == base + 1) ? 0.0f : na.y;
                nb.x = (c == base + 2) ? 0.0f : nb.x;
                nb.y = (c == base + 3) ? 0.0f : nb.y;
                v2f da = Aa * Ba,                     db = Ab_ * Bb_;
                float ra = __builtin_amdgcn_rcpf(da.x * da.y);
                float rb = __builtin_amdgcn_rcpf(db.x * db.y);
                v2f ia = { da.y * ra, da.x * ra };
                v2f ib = { db.y * rb, db.x * rb };
                aD = __builtin_elementwise_fma(na, ia, aD);
                aD = __builtin_elementwise_fma(nb, ib, aD);
            }
        }
    }

    float acc_s = 2.0f * (aO.x + aO.y) + (aD.x + aD.y);

    // ---- wave butterfly, block combine, salted atomic, counter-gated reduce
    #pragma unroll
    for (int off = 32; off > 0; off >>= 1)
        acc_s += __shfl_xor(acc_s, off, 64);

    __shared__ float wsum[WPB];
    __shared__ int lastflag;
    if (lane == 0) wsum[tid >> 6] = acc_s;
    __syncthreads();
    if (tid == 0) {
        float s = 0.0f;
        #pragma unroll
        for (int k = 0; k < WPB; ++k) s += wsum[k];
        atomicAdd(&slots[(blockIdx.x & (NSLOT - 1)) * SLOT_STRIDE], s);
        __threadfence();
        int old = atomicAdd(cnt, 1);
        lastflag = (old == NBLK - 1);
    }
    __syncthreads();
    if (lastflag) {
        __threadfence();
        float s = 0.0f;
        if (tid < NSLOT)
            s = __hip_atomic_load(&slots[tid * SLOT_STRIDE],
                                  __ATOMIC_ACQUIRE, __HIP_MEMORY_SCOPE_AGENT);
        #pragma unroll
        for (int off = 32; off > 0; off >>= 1)
            s += __shfl_xor(s, off, 64);
        if (lane == 0) wsum[tid >> 6] = s;
        __syncthreads();
        if (tid == 0) out[0] = wsum[0];   // all slots reduced within wave 0
    }
}

extern "C" void kernel_launch(void* const* d_in, const int* in_sizes, int n_in,
                              void* d_out, int out_size, void* d_ws, size_t ws_size,
                              hipStream_t stream) {
    // setup_inputs order: atomic_numbers(0), positions(1), r2r4(2), a1(3), a2(4), s6(5), s8(6)
    const float* pos = (const float*)d_in[1];
    const float* a1  = (const float*)d_in[3];
    const float* a2  = (const float*)d_in[4];
    const float* s6  = (const float*)d_in[5];
    const float* s8  = (const float*)d_in[6];
    char* ws = (char*)d_ws;
    uint4* Ab    = (uint4*)(ws + AB_OFF);
    uint4* Bb    = (uint4*)(ws + BB_OFF);
    float* Si    = (float*)(ws + SI_OFF);
    float* slots = (float*)(ws + SLOT_OFF);
    int*   cnt   = (int*)(ws + CNT_OFF);
    float* out   = (float*)d_out;

    prep<<<dim3(NA / 256), 256, 0, stream>>>(pos, Ab, Bb, Si);
    hipMemsetAsync(ws + SLOT_OFF, 0, NSLOT * SLOT_STRIDE * sizeof(float) + sizeof(int), stream);
    dftd3_mfma<<<dim3(NBLK), BLOCK, 0, stream>>>(Ab, Bb, Si, a1, a2, s6, s8,
                                                 slots, cnt, out);
}